// Round 1
// baseline (227.977 us; speedup 1.0000x reference)
//
#include <hip/hip_runtime.h>
#include <hip/hip_bf16.h>

// out[b,i] = sum_{j<=i} x[b,j] * kernel[i-j]   (causal Toeplitz matmul)
// B=2048 (M), N=4096, K=4096. f32 in/out, bf16 MFMA compute.
//
// Strategy:
//  - krev copies: 8 shifted copies of reversed zero-padded bf16 kernel so every
//    lane's 8-element B fragment is a 16B-aligned contiguous load (L1-resident).
//  - A = bf16(x) staged via global_load_lds (16B) into LDS, m97-style.
//  - Triangular skip: block with col tile n0 runs only (n0>>5)+4 K-steps.

typedef unsigned short u16;
typedef __attribute__((ext_vector_type(8))) short  bf16x8;
typedef __attribute__((ext_vector_type(8))) unsigned short u16x8;
typedef __attribute__((ext_vector_type(4))) float  f32x4;

#define KDIM 4096
#define NDIM 4096
#define MDIM 2048
#define KREV_STRIDE 4352            // elements per shifted copy
#define KREV_BYTES  (8 * KREV_STRIDE * 2)   // 69632

static __device__ inline u16 f2bf(float f) {
  unsigned u = __builtin_bit_cast(unsigned, f);
  unsigned r = u + 0x7FFFu + ((u >> 16) & 1u);
  return (u16)(r >> 16);
}

static __device__ inline void async_copy16(const void* g, void* l) {
  __builtin_amdgcn_global_load_lds((const __attribute__((address_space(1))) void*)g,
                                   (__attribute__((address_space(3))) void*)l,
                                   16, 0, 0);
}

// Build 8 shifted copies of reversed, zero-padded bf16 kernel.
// copy a, slot u  holds  krev_logical[u + a - 8], krev_logical[t] = kern[4095-t] for t in [0,4095] else 0.
__global__ __launch_bounds__(256) void build_krev(const float* __restrict__ kern,
                                                  u16* __restrict__ krevs) {
  int a = blockIdx.x;                       // 0..7
  int u = blockIdx.y * 256 + threadIdx.x;   // 0..4351
  int t = u + a - 8;
  u16 v = 0;
  if (t >= 0 && t <= 4095) v = f2bf(kern[4095 - t]);
  krevs[a * KREV_STRIDE + u] = v;
}

__global__ __launch_bounds__(256) void convert_x(const float* __restrict__ x,
                                                 u16* __restrict__ xb) {
  size_t i = ((size_t)blockIdx.x * 256 + threadIdx.x) * 8;
  const f32x4* p = (const f32x4*)(x + i);
  f32x4 v0 = p[0], v1 = p[1];
  u16x8 r;
  r[0] = f2bf(v0[0]); r[1] = f2bf(v0[1]); r[2] = f2bf(v0[2]); r[3] = f2bf(v0[3]);
  r[4] = f2bf(v1[0]); r[5] = f2bf(v1[1]); r[6] = f2bf(v1[2]); r[7] = f2bf(v1[3]);
  *(u16x8*)(xb + i) = r;
}

// CONV=false: A is pre-converted bf16 (global_load_lds staging).
// CONV=true : A is f32, convert during staging (ws too small for xb).
template <bool CONV>
__global__ __launch_bounds__(256) void toeplitz_gemm(const void* __restrict__ Av,
                                                     const u16* __restrict__ krevs,
                                                     float* __restrict__ out) {
  __shared__ u16 A_lds[128 * 32];   // 8 KB, rows of 32 bf16 (64 B)

  const int tid  = threadIdx.x;
  const int w    = tid >> 6;        // wave 0..3
  const int lane = tid & 63;
  const int lane16 = lane & 15;
  const int quad   = lane >> 4;
  const int wm = w & 1;             // wave row (m)
  const int wn = w >> 1;            // wave col (n)

  const int n0 = ((int)gridDim.x - 1 - (int)blockIdx.x) * 128;  // heavy blocks first
  const int m0 = (int)blockIdx.y * 128;

  // B fragment base pointers: element j of frag = kern[n_g - (k0+quad*8+j)]
  //   = krev_logical[s0 + k0 + j],  s0 = 4095 - n_g + quad*8.
  // copy a = s0&7 makes the 16B load aligned; a is K-loop invariant.
  const u16* bptr[4];
  for (int fn = 0; fn < 4; ++fn) {
    int n_g = n0 + wn * 64 + fn * 16 + lane16;
    int s0  = 4095 - n_g + quad * 8;
    int a   = s0 & 7;
    int u0  = s0 - a + 8;
    bptr[fn] = krevs + a * KREV_STRIDE + u0;
  }

  f32x4 acc[4][4] = {};

  bf16x8 bcur[4], bnext[4];
  for (int fn = 0; fn < 4; ++fn) bcur[fn] = *(const bf16x8*)(bptr[fn]);

  const int nk = (n0 >> 5) + 4;     // triangular skip: k0 < n0+128

  for (int ks = 0; ks < nk; ++ks) {
    const int k0 = ks * 32;
    __syncthreads();                // protect LDS from overwrite
    if constexpr (CONV) {
      const float* x = (const float*)Av;
      int row  = tid >> 1;
      int colb = (tid & 1) * 16;
      const f32x4* px = (const f32x4*)(x + (size_t)(m0 + row) * KDIM + k0 + colb);
      f32x4 v0 = px[0], v1 = px[1], v2 = px[2], v3 = px[3];
      u16x8 r0, r1;
      r0[0]=f2bf(v0[0]); r0[1]=f2bf(v0[1]); r0[2]=f2bf(v0[2]); r0[3]=f2bf(v0[3]);
      r0[4]=f2bf(v1[0]); r0[5]=f2bf(v1[1]); r0[6]=f2bf(v1[2]); r0[7]=f2bf(v1[3]);
      r1[0]=f2bf(v2[0]); r1[1]=f2bf(v2[1]); r1[2]=f2bf(v2[2]); r1[3]=f2bf(v2[3]);
      r1[4]=f2bf(v3[0]); r1[5]=f2bf(v3[1]); r1[6]=f2bf(v3[2]); r1[7]=f2bf(v3[3]);
      *(u16x8*)(&A_lds[row * 32 + colb])     = r0;
      *(u16x8*)(&A_lds[row * 32 + colb + 8]) = r1;
    } else {
      const u16* xb = (const u16*)Av;
      for (int c = 0; c < 2; ++c) {
        int row = c * 64 + w * 16 + (lane >> 2);
        int col = (lane & 3) * 8;
        const u16* gp = xb + (size_t)(m0 + row) * KDIM + k0 + col;
        u16* lp = &A_lds[c * 2048 + w * 512];   // wave-uniform base; HW adds lane*16B
        async_copy16(gp, lp);
      }
    }
    // prefetch next-step B fragments (no barrier dependency; overshoot reads zeros)
    for (int fn = 0; fn < 4; ++fn)
      bnext[fn] = *(const bf16x8*)(bptr[fn] + (ks + 1) * 32);
    __syncthreads();                // data ready (drains vmcnt)

    bf16x8 af[4];
    for (int fm = 0; fm < 4; ++fm) {
      int row = wm * 64 + fm * 16 + lane16;
      af[fm] = *(const bf16x8*)(&A_lds[row * 32 + quad * 8]);
    }
    for (int fm = 0; fm < 4; ++fm)
      for (int fn = 0; fn < 4; ++fn)
        acc[fm][fn] = __builtin_amdgcn_mfma_f32_16x16x32_bf16(af[fm], bcur[fn], acc[fm][fn], 0, 0, 0);
    for (int fn = 0; fn < 4; ++fn) bcur[fn] = bnext[fn];
  }

  // epilogue: C/D layout col=lane&15, row=quad*4+r
  for (int fm = 0; fm < 4; ++fm) {
    int row_base = m0 + wm * 64 + fm * 16 + quad * 4;
    for (int fn = 0; fn < 4; ++fn) {
      int col = n0 + wn * 64 + fn * 16 + lane16;
      for (int r = 0; r < 4; ++r)
        out[(size_t)(row_base + r) * NDIM + col] = acc[fm][fn][r];
    }
  }
}

extern "C" void kernel_launch(void* const* d_in, const int* in_sizes, int n_in,
                              void* d_out, int out_size, void* d_ws, size_t ws_size,
                              hipStream_t stream) {
  const float* x    = (const float*)d_in[0];
  const float* kern = (const float*)d_in[1];
  float* out = (float*)d_out;

  u16* krevs = (u16*)d_ws;
  build_krev<<<dim3(8, 17), 256, 0, stream>>>(kern, krevs);

  const size_t need_fast = (size_t)KREV_BYTES + (size_t)MDIM * KDIM * 2;  // ~16.1 MiB
  dim3 grid(NDIM / 128, MDIM / 128);  // 32 x 16

  if (ws_size >= need_fast) {
    u16* xb = (u16*)((char*)d_ws + KREV_BYTES);
    convert_x<<<(MDIM * KDIM) / (256 * 8), 256, 0, stream>>>(x, xb);
    toeplitz_gemm<false><<<grid, 256, 0, stream>>>(xb, krevs, out);
  } else {
    toeplitz_gemm<true><<<grid, 256, 0, stream>>>(x, krevs, out);
  }
}

// Round 2
// 189.631 us; speedup vs baseline: 1.2022x; 1.2022x over previous
//
#include <hip/hip_runtime.h>
#include <hip/hip_bf16.h>

// out[b,i] = sum_{j<=i} x[b,j] * kernel[i-j]   (causal Toeplitz matmul)
// M=2048, N=K=4096. f32 in/out, bf16 MFMA compute.
//
// R2: 512-thread blocks (8 waves) on 128x128 tiles, BK=64, boustrophedon
// block->work mapping for exact load balance (68 K-steps per mod-256 class),
// XOR source-swizzle so ds_read_b128 fragment reads are conflict-free.

typedef unsigned short u16;
typedef __attribute__((ext_vector_type(8))) short  bf16x8;
typedef __attribute__((ext_vector_type(8))) unsigned short u16x8;
typedef __attribute__((ext_vector_type(4))) float  f32x4;

#define KDIM 4096
#define NDIM 4096
#define MDIM 2048
#define KREV_STRIDE 4352
#define KREV_BYTES  (8 * KREV_STRIDE * 2)

static __device__ inline u16 f2bf(float f) {
  unsigned u = __builtin_bit_cast(unsigned, f);
  unsigned r = u + 0x7FFFu + ((u >> 16) & 1u);
  return (u16)(r >> 16);
}

static __device__ inline void async_copy16(const void* g, void* l) {
  __builtin_amdgcn_global_load_lds((const __attribute__((address_space(1))) void*)g,
                                   (__attribute__((address_space(3))) void*)l,
                                   16, 0, 0);
}

// 8 shifted copies of reversed zero-padded bf16 kernel:
// copy a, slot u holds krev_logical[u + a - 8]; krev_logical[t]=kern[4095-t], 0 outside.
__global__ __launch_bounds__(256) void build_krev(const float* __restrict__ kern,
                                                  u16* __restrict__ krevs) {
  int a = blockIdx.x;
  int u = blockIdx.y * 256 + threadIdx.x;
  int t = u + a - 8;
  u16 v = 0;
  if (t >= 0 && t <= 4095) v = f2bf(kern[4095 - t]);
  krevs[a * KREV_STRIDE + u] = v;
}

__global__ __launch_bounds__(256) void convert_x(const float* __restrict__ x,
                                                 u16* __restrict__ xb) {
  size_t i = ((size_t)blockIdx.x * 256 + threadIdx.x) * 8;
  const f32x4* p = (const f32x4*)(x + i);
  f32x4 v0 = p[0], v1 = p[1];
  u16x8 r;
  r[0] = f2bf(v0[0]); r[1] = f2bf(v0[1]); r[2] = f2bf(v0[2]); r[3] = f2bf(v0[3]);
  r[4] = f2bf(v1[0]); r[5] = f2bf(v1[1]); r[6] = f2bf(v1[2]); r[7] = f2bf(v1[3]);
  *(u16x8*)(xb + i) = r;
}

template <bool CONV>
__global__ __launch_bounds__(512, 4) void toeplitz_gemm(const void* __restrict__ Av,
                                                        const u16* __restrict__ krevs,
                                                        float* __restrict__ out) {
  __shared__ u16 A_lds[128 * 64];   // 16 KB, rows of 64 bf16 (128 B)

  const int tid  = threadIdx.x;
  const int w    = tid >> 6;        // 0..7
  const int lane = tid & 63;
  const int lane16 = lane & 15;
  const int quad   = lane >> 4;
  const int wm = w >> 2;            // 0..1  (wave row)
  const int wn = w & 3;             // 0..3  (wave col)

  // boustrophedon rank mapping: class j = b&255 gets ranks {j, 511-j};
  // nk(rank j) + nk(rank 511-j) == 68 for every j  -> uniform work per class.
  const int b    = (int)blockIdx.x;
  const int rank = (b < 256) ? b : 511 - (b & 255);
  const int ct   = 31 - (rank >> 4);      // column tile, heavy (31) first
  const int n0   = ct * 128;
  const int m0   = (rank & 15) * 128;

  // B fragment pointers: frag elem j (fn,kk) = kern[n_g - (ks*64+kk*32+quad*8+j)]
  //   = krev_logical[s0 + ks*64 + kk*32 + j], s0 = 4095 - n_g + quad*8.
  const u16* bptr[2];
  for (int fn = 0; fn < 2; ++fn) {
    int n_g = n0 + wn * 32 + fn * 16 + lane16;
    int s0  = 4095 - n_g + quad * 8;
    int a   = s0 & 7;
    int u0  = s0 - a + 8;
    bptr[fn] = krevs + a * KREV_STRIDE + u0;
  }

  f32x4 acc[4][2] = {};
  bf16x8 bcur[2][2], bnext[2][2];
  for (int fn = 0; fn < 2; ++fn)
    for (int kk = 0; kk < 2; ++kk)
      bcur[fn][kk] = *(const bf16x8*)(bptr[fn] + kk * 32);

  const int nk = 2 * ct + 2;        // BK=64 steps; covers k < n0+128

  const int srow  = (w << 3) + (lane >> 3);     // staging row (round adds 64)
  const int schunk = (lane & 7);                // physical 16B chunk
  const int r7 = srow & 7;

  for (int ks = 0; ks < nk; ++ks) {
    const int k0 = ks * 64;
    __syncthreads();
    if constexpr (CONV) {
      const float* x = (const float*)Av;
      for (int c = 0; c < 2; ++c) {
        int row = c * 64 + srow;
        int src = (schunk ^ (row & 7)) * 8;
        const f32x4* px = (const f32x4*)(x + (size_t)(m0 + row) * KDIM + k0 + src);
        f32x4 v0 = px[0], v1 = px[1];
        u16x8 r;
        r[0]=f2bf(v0[0]); r[1]=f2bf(v0[1]); r[2]=f2bf(v0[2]); r[3]=f2bf(v0[3]);
        r[4]=f2bf(v1[0]); r[5]=f2bf(v1[1]); r[6]=f2bf(v1[2]); r[7]=f2bf(v1[3]);
        *(u16x8*)(&A_lds[row * 64 + schunk * 8]) = r;
      }
    } else {
      const u16* xb = (const u16*)Av;
      for (int c = 0; c < 2; ++c) {
        int row = c * 64 + srow;
        // physical chunk p=lane&7 receives logical chunk p^(row&7) (XOR swizzle
        // applied to the SOURCE address; dest is lane-contiguous for global_load_lds)
        const u16* gp = xb + (size_t)(m0 + row) * KDIM + k0 + ((schunk ^ r7) << 3);
        u16* lp = &A_lds[c * 4096 + w * 512];   // wave-uniform; HW adds lane*16B
        async_copy16(gp, lp);
      }
    }
    // prefetch next-step B fragments (overshoot reads zero padding)
    for (int fn = 0; fn < 2; ++fn)
      for (int kk = 0; kk < 2; ++kk)
        bnext[fn][kk] = *(const bf16x8*)(bptr[fn] + (ks + 1) * 64 + kk * 32);
    __syncthreads();

    for (int kk = 0; kk < 2; ++kk) {
      bf16x8 af[4];
      for (int fm = 0; fm < 4; ++fm) {
        int row = wm * 64 + fm * 16 + lane16;
        int l   = kk * 4 + quad;                 // logical 16B chunk
        int p   = l ^ (row & 7);                 // physical (XOR swizzle)
        af[fm] = *(const bf16x8*)(&A_lds[row * 64 + p * 8]);
      }
      for (int fm = 0; fm < 4; ++fm)
        for (int fn = 0; fn < 2; ++fn)
          acc[fm][fn] = __builtin_amdgcn_mfma_f32_16x16x32_bf16(af[fm], bcur[fn][kk], acc[fm][fn], 0, 0, 0);
    }
    for (int fn = 0; fn < 2; ++fn)
      for (int kk = 0; kk < 2; ++kk)
        bcur[fn][kk] = bnext[fn][kk];
  }

  // epilogue: C/D layout col=lane&15, row=quad*4+r
  for (int fm = 0; fm < 4; ++fm) {
    int row_base = m0 + wm * 64 + fm * 16 + quad * 4;
    for (int fn = 0; fn < 2; ++fn) {
      int col = n0 + wn * 32 + fn * 16 + lane16;
      for (int r = 0; r < 4; ++r)
        out[(size_t)(row_base + r) * NDIM + col] = acc[fm][fn][r];
    }
  }
}

extern "C" void kernel_launch(void* const* d_in, const int* in_sizes, int n_in,
                              void* d_out, int out_size, void* d_ws, size_t ws_size,
                              hipStream_t stream) {
  const float* x    = (const float*)d_in[0];
  const float* kern = (const float*)d_in[1];
  float* out = (float*)d_out;

  u16* krevs = (u16*)d_ws;
  build_krev<<<dim3(8, 17), 256, 0, stream>>>(kern, krevs);

  const size_t need_fast = (size_t)KREV_BYTES + (size_t)MDIM * KDIM * 2;
  dim3 grid(512);

  if (ws_size >= need_fast) {
    u16* xb = (u16*)((char*)d_ws + KREV_BYTES);
    convert_x<<<(MDIM * KDIM) / (256 * 8), 256, 0, stream>>>(x, xb);
    toeplitz_gemm<false><<<grid, 512, 0, stream>>>(xb, krevs, out);
  } else {
    toeplitz_gemm<true><<<grid, 512, 0, stream>>>(x, krevs, out);
  }
}

// Round 3
// 137.773 us; speedup vs baseline: 1.6547x; 1.3764x over previous
//
#include <hip/hip_runtime.h>
#include <hip/hip_bf16.h>

// out[b,i] = sum_{j<=i} x[b,j] * kernel[i-j]   (causal Toeplitz matmul)
// M=2048, N=K=4096. f32 in/out, bf16 MFMA compute.
//
// R3: B fragments now come from LDS (8 shifted copies of the kernel window,
// copy stride 520 elems -> copies 4 banks apart -> conflict-free b128 reads),
// staged per 256-k chunk with 2 coalesced global_load_lds per wave. This kills
// the per-lane-scattered global B reads that were L1-request-rate-bound
// (~4000 cyc/K-step in R2). 256-thread blocks, 4 waves x 4x4 frags (64x64),
// 2:1 MFMA:ds_read_b128 ratio. prep fuses krev build + x->bf16 convert.

typedef unsigned short u16;
typedef __attribute__((ext_vector_type(8))) short  bf16x8;
typedef __attribute__((ext_vector_type(8))) unsigned short u16x8;
typedef __attribute__((ext_vector_type(4))) float  f32x4;

#define KDIM 4096
#define NDIM 4096
#define MDIM 2048
#define KREV_STRIDE 4608                    // elems per shifted copy (covers W+kc+512 max 4480)
#define KREV_BYTES  (8 * KREV_STRIDE * 2)   // 73728
#define BSTRIDE 520                         // LDS B copy stride (elems): 1040 B -> +4 banks/copy

static __device__ inline u16 f2bf(float f) {
  unsigned u = __builtin_bit_cast(unsigned, f);
  unsigned r = u + 0x7FFFu + ((u >> 16) & 1u);
  return (u16)(r >> 16);
}

static __device__ inline void async_copy16(const void* g, void* l) {
  __builtin_amdgcn_global_load_lds((const __attribute__((address_space(1))) void*)g,
                                   (__attribute__((address_space(3))) void*)l,
                                   16, 0, 0);
}

// Fused prep: blocks [0, conv_blocks) convert x->bf16 (8 elems/thread);
// blocks [conv_blocks, conv_blocks+18) build 8 shifted krev copies.
// krevs[a][u] = krev_logical[u + a - 8]; krev_logical[t] = kern[4095-t] for t in [0,4096) else 0.
__global__ __launch_bounds__(256) void prep(const float* __restrict__ x,
                                            const float* __restrict__ kern,
                                            u16* __restrict__ xb,
                                            u16* __restrict__ krevs,
                                            int conv_blocks) {
  int kb = (int)blockIdx.x - conv_blocks;
  if (kb >= 0) {
    int u = kb * 256 + threadIdx.x;          // 0..4607
    for (int a = 0; a < 8; ++a) {
      int t = u + a - 8;
      u16 v = 0;
      if (t >= 0 && t <= 4095) v = f2bf(kern[4095 - t]);
      krevs[a * KREV_STRIDE + u] = v;
    }
  } else {
    size_t i = ((size_t)blockIdx.x * 256 + threadIdx.x) * 8;
    const f32x4* p = (const f32x4*)(x + i);
    f32x4 v0 = p[0], v1 = p[1];
    u16x8 r;
    r[0] = f2bf(v0[0]); r[1] = f2bf(v0[1]); r[2] = f2bf(v0[2]); r[3] = f2bf(v0[3]);
    r[4] = f2bf(v1[0]); r[5] = f2bf(v1[1]); r[6] = f2bf(v1[2]); r[7] = f2bf(v1[3]);
    *(u16x8*)(xb + i) = r;
  }
}

template <bool CONV>
__global__ __launch_bounds__(256, 2) void toeplitz_gemm(const void* __restrict__ Av,
                                                        const u16* __restrict__ krevs,
                                                        float* __restrict__ out) {
  __shared__ u16 A_lds[128 * 64];      // 16 KB, rows of 64 bf16, XOR chunk swizzle
  __shared__ u16 B_lds[8 * BSTRIDE];   // 8.3 KB, 8 shifted copies of kernel window

  const int tid  = threadIdx.x;
  const int w    = tid >> 6;        // 0..3
  const int lane = tid & 63;
  const int lane16 = lane & 15;
  const int quad   = lane >> 4;
  const int wm = w >> 1;            // 0..1
  const int wn = w & 1;             // 0..1

  // boustrophedon: class j = b&255 gets ranks {j, 511-j}; nk sums to 68/class.
  const int b    = (int)blockIdx.x;
  const int rank = (b < 256) ? b : 511 - (b & 255);
  const int ct   = 31 - (rank >> 4);      // column tile, heavy first
  const int n0   = ct * 128;
  const int m0   = (rank & 15) * 128;
  const int W    = 3968 - n0;             // B window base (mult of 8)

  // B LDS fragment offsets: elem j of frag(fn,kk,ks) = krev_logical[s0 + ks*64 + kk*32 + j],
  // s0 = 4095 - n_g + quad*8. LDS copy a holds krev_logical[W + kc + u + a - 8].
  int boff[4];                            // element offset of frag start (ks&3==0, kk=0)
  for (int fn = 0; fn < 4; ++fn) {
    int n_g = n0 + wn * 64 + fn * 16 + lane16;
    int s0  = 4095 - n_g + quad * 8;
    int a   = s0 & 7;
    int ub  = s0 - a + 8 - W;             // in [8, 152], mult of 8
    boff[fn] = a * BSTRIDE + ub;
  }

  f32x4 acc[4][4] = {};
  const int nk = 2 * ct + 2;              // BK=64 steps; covers k < n0+128

  const int srow8  = lane >> 3;           // row-within-8-group
  const int ssrc   = ((lane & 7) ^ srow8) * 8;   // XOR source swizzle (16B chunks)

  for (int ks = 0; ks < nk; ++ks) {
    const int k0 = ks * 64;
    __syncthreads();                      // protect LDS (A every step, B every 4th)
    if ((ks & 3) == 0) {
      // stage B chunk: copy c gets krevs[c][W+k0 .. +512), 1 wave-instr per copy
      for (int cc = 0; cc < 2; ++cc) {
        int c = cc * 4 + w;
        async_copy16(krevs + c * KREV_STRIDE + W + k0 + (lane << 3),
                     &B_lds[c * BSTRIDE]);
      }
    }
    if constexpr (CONV) {
      const float* x = (const float*)Av;
      int row  = tid & 127;
      int colq = tid >> 7;                // 0..1, 32 cols each
      for (int lc = 0; lc < 4; ++lc) {
        int l = colq * 4 + lc;            // logical 16B chunk
        int p = l ^ (row & 7);            // physical (XOR swizzle)
        const f32x4* px = (const f32x4*)(x + (size_t)(m0 + row) * KDIM + k0 + l * 8);
        f32x4 v0 = px[0], v1 = px[1];
        u16x8 r;
        r[0]=f2bf(v0[0]); r[1]=f2bf(v0[1]); r[2]=f2bf(v0[2]); r[3]=f2bf(v0[3]);
        r[4]=f2bf(v1[0]); r[5]=f2bf(v1[1]); r[6]=f2bf(v1[2]); r[7]=f2bf(v1[3]);
        *(u16x8*)(&A_lds[row * 64 + p * 8]) = r;
      }
    } else {
      const u16* xb = (const u16*)Av;
      for (int c = 0; c < 4; ++c) {
        int g   = c * 4 + w;              // 8-row group 0..15
        int row = g * 8 + srow8;
        async_copy16(xb + (size_t)(m0 + row) * KDIM + k0 + ssrc,
                     &A_lds[g * 512]);    // wave-uniform base; HW adds lane*16B
      }
    }
    __syncthreads();                      // data ready (drains vmcnt)

    const int ksl = (ks & 3) * 64;
    for (int kk = 0; kk < 2; ++kk) {
      bf16x8 af[4];
      const int p = (kk * 4 + quad) ^ (lane16 & 7);
      for (int fm = 0; fm < 4; ++fm) {
        int row = wm * 64 + fm * 16 + lane16;
        af[fm] = *(const bf16x8*)(&A_lds[row * 64 + p * 8]);
      }
      bf16x8 bf[4];
      for (int fn = 0; fn < 4; ++fn)
        bf[fn] = *(const bf16x8*)(&B_lds[boff[fn] + ksl + kk * 32]);
      for (int fm = 0; fm < 4; ++fm)
        for (int fn = 0; fn < 4; ++fn)
          acc[fm][fn] = __builtin_amdgcn_mfma_f32_16x16x32_bf16(af[fm], bf[fn], acc[fm][fn], 0, 0, 0);
    }
  }

  // epilogue: C/D layout col=lane&15, row=quad*4+r
  for (int fm = 0; fm < 4; ++fm) {
    int row_base = m0 + wm * 64 + fm * 16 + quad * 4;
    for (int fn = 0; fn < 4; ++fn) {
      int col = n0 + wn * 64 + fn * 16 + lane16;
      for (int r = 0; r < 4; ++r)
        out[(size_t)(row_base + r) * NDIM + col] = acc[fm][fn][r];
    }
  }
}

extern "C" void kernel_launch(void* const* d_in, const int* in_sizes, int n_in,
                              void* d_out, int out_size, void* d_ws, size_t ws_size,
                              hipStream_t stream) {
  const float* x    = (const float*)d_in[0];
  const float* kern = (const float*)d_in[1];
  float* out = (float*)d_out;

  u16* krevs = (u16*)d_ws;
  u16* xb    = (u16*)((char*)d_ws + KREV_BYTES);
  const size_t need_fast = (size_t)KREV_BYTES + (size_t)MDIM * KDIM * 2;

  if (ws_size >= need_fast) {
    prep<<<4096 + 18, 256, 0, stream>>>(x, kern, xb, krevs, 4096);
    toeplitz_gemm<false><<<512, 256, 0, stream>>>(xb, krevs, out);
  } else {
    prep<<<18, 256, 0, stream>>>(x, kern, xb, krevs, 0);
    toeplitz_gemm<true><<<512, 256, 0, stream>>>(x, krevs, out);
  }
}

// Round 4
// 135.865 us; speedup vs baseline: 1.6780x; 1.0140x over previous
//
#include <hip/hip_runtime.h>
#include <hip/hip_bf16.h>

// out[b,i] = sum_{j<=i} x[b,j] * kernel[i-j]   (causal Toeplitz matmul)
// M=2048, N=K=4096. f32 in/out, bf16 MFMA compute.
//
// R4: single-barrier double-buffered pipeline. R3 was critical-chain bound:
// heavy block (nk=66) runs alone at ~2180 cyc/step because each step serially
// exposes global->LDS latency (stage; barrier drains vmcnt(0); compute).
// Now stage(ks+1) issues after the barrier into the ping-pong buffer and is
// drained one full compute phase later. 1 barrier/step instead of 2.

typedef unsigned short u16;
typedef __attribute__((ext_vector_type(8))) short  bf16x8;
typedef __attribute__((ext_vector_type(8))) unsigned short u16x8;
typedef __attribute__((ext_vector_type(4))) float  f32x4;

#define KDIM 4096
#define NDIM 4096
#define MDIM 2048
#define KREV_STRIDE 4608                    // elems per shifted copy
#define KREV_BYTES  (8 * KREV_STRIDE * 2)   // 73728
#define BSTRIDE 520                         // LDS B copy stride (elems)

static __device__ inline u16 f2bf(float f) {
  unsigned u = __builtin_bit_cast(unsigned, f);
  unsigned r = u + 0x7FFFu + ((u >> 16) & 1u);
  return (u16)(r >> 16);
}

static __device__ inline void async_copy16(const void* g, void* l) {
  __builtin_amdgcn_global_load_lds((const __attribute__((address_space(1))) void*)g,
                                   (__attribute__((address_space(3))) void*)l,
                                   16, 0, 0);
}

// Fused prep: blocks [0, conv_blocks) convert x->bf16; last 18 blocks build
// 8 shifted krev copies. krevs[a][u] = krev_logical[u+a-8];
// krev_logical[t] = kern[4095-t] for t in [0,4096) else 0.
__global__ __launch_bounds__(256) void prep(const float* __restrict__ x,
                                            const float* __restrict__ kern,
                                            u16* __restrict__ xb,
                                            u16* __restrict__ krevs,
                                            int conv_blocks) {
  int kb = (int)blockIdx.x - conv_blocks;
  if (kb >= 0) {
    int u = kb * 256 + threadIdx.x;
    for (int a = 0; a < 8; ++a) {
      int t = u + a - 8;
      u16 v = 0;
      if (t >= 0 && t <= 4095) v = f2bf(kern[4095 - t]);
      krevs[a * KREV_STRIDE + u] = v;
    }
  } else {
    size_t i = ((size_t)blockIdx.x * 256 + threadIdx.x) * 8;
    const f32x4* p = (const f32x4*)(x + i);
    f32x4 v0 = p[0], v1 = p[1];
    u16x8 r;
    r[0] = f2bf(v0[0]); r[1] = f2bf(v0[1]); r[2] = f2bf(v0[2]); r[3] = f2bf(v0[3]);
    r[4] = f2bf(v1[0]); r[5] = f2bf(v1[1]); r[6] = f2bf(v1[2]); r[7] = f2bf(v1[3]);
    *(u16x8*)(xb + i) = r;
  }
}

template <bool CONV>
__global__ __launch_bounds__(256, 3) void toeplitz_gemm(const void* __restrict__ Av,
                                                        const u16* __restrict__ krevs,
                                                        float* __restrict__ out) {
  __shared__ u16 A_lds[2][128 * 64];     // 2 x 16 KB, XOR chunk swizzle
  __shared__ u16 B_lds[2][8 * BSTRIDE];  // 2 x 8.3 KB, 8 shifted kernel copies

  const int tid  = threadIdx.x;
  const int w    = tid >> 6;
  const int lane = tid & 63;
  const int lane16 = lane & 15;
  const int quad   = lane >> 4;
  const int wm = w >> 1;
  const int wn = w & 1;

  // boustrophedon: class j = b&255 gets ranks {j, 511-j} (equal per-CU totals)
  const int b    = (int)blockIdx.x;
  const int rank = (b < 256) ? b : 511 - (b & 255);
  const int ct   = 31 - (rank >> 4);
  const int n0   = ct * 128;
  const int m0   = (rank & 15) * 128;
  const int W    = 3968 - n0;

  // B LDS fragment offsets: elem j of frag(fn,kk,ks) = krev_logical[s0+ks*64+kk*32+j],
  // s0 = 4095 - n_g + quad*8; LDS copy a holds krev_logical[W + ch*256 + u + a - 8].
  int boff[4];
  for (int fn = 0; fn < 4; ++fn) {
    int n_g = n0 + wn * 64 + fn * 16 + lane16;
    int s0  = 4095 - n_g + quad * 8;
    int a   = s0 & 7;
    int ub  = s0 - a + 8 - W;
    boff[fn] = a * BSTRIDE + ub;
  }

  f32x4 acc[4][4] = {};
  const int nk = 2 * ct + 2;

  const int srow8 = lane >> 3;
  const int ssrc  = ((lane & 7) ^ srow8) * 8;   // XOR source swizzle (16B chunks)

  const u16* xb = (const u16*)Av;
  const float* xf = (const float*)Av;

  auto stageA = [&](int ks) {
    const int buf = ks & 1;
    const int k0  = ks * 64;
    if constexpr (CONV) {
      int row  = tid & 127;
      int colq = tid >> 7;
      for (int lc = 0; lc < 4; ++lc) {
        int l = colq * 4 + lc;
        int p = l ^ (row & 7);
        const f32x4* px = (const f32x4*)(xf + (size_t)(m0 + row) * KDIM + k0 + l * 8);
        f32x4 v0 = px[0], v1 = px[1];
        u16x8 r;
        r[0]=f2bf(v0[0]); r[1]=f2bf(v0[1]); r[2]=f2bf(v0[2]); r[3]=f2bf(v0[3]);
        r[4]=f2bf(v1[0]); r[5]=f2bf(v1[1]); r[6]=f2bf(v1[2]); r[7]=f2bf(v1[3]);
        *(u16x8*)(&A_lds[buf][row * 64 + p * 8]) = r;
      }
    } else {
      for (int c = 0; c < 4; ++c) {
        int g   = c * 4 + w;
        int row = g * 8 + srow8;
        async_copy16(xb + (size_t)(m0 + row) * KDIM + k0 + ssrc,
                     &A_lds[buf][g * 512]);
      }
    }
  };
  auto stageB = [&](int ch) {
    const int bb = ch & 1;
    for (int cc = 0; cc < 2; ++cc) {
      int c = cc * 4 + w;
      async_copy16(krevs + c * KREV_STRIDE + W + ch * 256 + (lane << 3),
                   &B_lds[bb][c * BSTRIDE]);
    }
  };

  // prologue
  stageB(0);
  stageA(0);

  for (int ks = 0; ks < nk; ++ks) {
    __syncthreads();          // stage(ks) complete (vmcnt drain); prior reads done
    const int nxt = ks + 1;
    if (nxt < nk) {
      stageA(nxt);
      if ((nxt & 3) == 0) stageB(nxt >> 2);
    }
    const u16* Ab = A_lds[ks & 1];
    const u16* Bb = B_lds[(ks >> 2) & 1];
    const int ksl = (ks & 3) * 64;
    for (int kk = 0; kk < 2; ++kk) {
      bf16x8 af[4];
      const int p = (kk * 4 + quad) ^ (lane16 & 7);
      for (int fm = 0; fm < 4; ++fm) {
        int row = wm * 64 + fm * 16 + lane16;
        af[fm] = *(const bf16x8*)(&Ab[row * 64 + p * 8]);
      }
      bf16x8 bf[4];
      for (int fn = 0; fn < 4; ++fn)
        bf[fn] = *(const bf16x8*)(&Bb[boff[fn] + ksl + kk * 32]);
      for (int fm = 0; fm < 4; ++fm)
        for (int fn = 0; fn < 4; ++fn)
          acc[fm][fn] = __builtin_amdgcn_mfma_f32_16x16x32_bf16(af[fm], bf[fn], acc[fm][fn], 0, 0, 0);
    }
  }

  // epilogue: C/D layout col=lane&15, row=quad*4+r
  for (int fm = 0; fm < 4; ++fm) {
    int row_base = m0 + wm * 64 + fm * 16 + quad * 4;
    for (int fn = 0; fn < 4; ++fn) {
      int col = n0 + wn * 64 + fn * 16 + lane16;
      for (int r = 0; r < 4; ++r)
        out[(size_t)(row_base + r) * NDIM + col] = acc[fm][fn][r];
    }
  }
}

extern "C" void kernel_launch(void* const* d_in, const int* in_sizes, int n_in,
                              void* d_out, int out_size, void* d_ws, size_t ws_size,
                              hipStream_t stream) {
  const float* x    = (const float*)d_in[0];
  const float* kern = (const float*)d_in[1];
  float* out = (float*)d_out;

  u16* krevs = (u16*)d_ws;
  u16* xb    = (u16*)((char*)d_ws + KREV_BYTES);
  const size_t need_fast = (size_t)KREV_BYTES + (size_t)MDIM * KDIM * 2;

  if (ws_size >= need_fast) {
    prep<<<4096 + 18, 256, 0, stream>>>(x, kern, xb, krevs, 4096);
    toeplitz_gemm<false><<<512, 256, 0, stream>>>(xb, krevs, out);
  } else {
    prep<<<18, 256, 0, stream>>>(x, kern, xb, krevs, 0);
    toeplitz_gemm<true><<<512, 256, 0, stream>>>(x, krevs, out);
  }
}

// Round 5
// 125.894 us; speedup vs baseline: 1.8109x; 1.0792x over previous
//
#include <hip/hip_runtime.h>
#include <hip/hip_bf16.h>

// out[b,i] = sum_{j<=i} x[b,j] * kernel[i-j]   (causal Toeplitz matmul)
// M=2048, N=K=4096. f32 in/out, bf16 MFMA compute.
//
// R5: intra-block split-K. 512-thread blocks (8 waves = 2 K-groups x 4 waves)
// on one 128x128 tile; group g handles interleaved BK=64 slices k = t*128+g*64,
// so both groups share one B chunk buffer. Heavy chain 66 -> 33 steps and the
// CU runs 8 waves instead of 4 (R4 post-mortem: 1 wave/SIMD exposed all lgkm /
// barrier bubbles -> 2245 cyc/step vs ~1000 cyc LDS-port floor). Partials
// combined via 2-round LDS exchange (no atomics, no extra HBM traffic).

typedef unsigned short u16;
typedef __attribute__((ext_vector_type(8))) short  bf16x8;
typedef __attribute__((ext_vector_type(8))) unsigned short u16x8;
typedef __attribute__((ext_vector_type(4))) float  f32x4;

#define KDIM 4096
#define NDIM 4096
#define MDIM 2048
#define KREV_STRIDE 4608                    // elems per shifted copy
#define KREV_BYTES  (8 * KREV_STRIDE * 2)   // 73728
#define BSTRIDE 520                         // LDS B copy stride (elems)

static __device__ inline u16 f2bf(float f) {
  unsigned u = __builtin_bit_cast(unsigned, f);
  unsigned r = u + 0x7FFFu + ((u >> 16) & 1u);
  return (u16)(r >> 16);
}

static __device__ inline void async_copy16(const void* g, void* l) {
  __builtin_amdgcn_global_load_lds((const __attribute__((address_space(1))) void*)g,
                                   (__attribute__((address_space(3))) void*)l,
                                   16, 0, 0);
}

// Fused prep: blocks [0, conv_blocks) convert x->bf16; last 18 blocks build
// 8 shifted krev copies. krevs[a][u] = krev_logical[u+a-8];
// krev_logical[t] = kern[4095-t] for t in [0,4096) else 0.
__global__ __launch_bounds__(256) void prep(const float* __restrict__ x,
                                            const float* __restrict__ kern,
                                            u16* __restrict__ xb,
                                            u16* __restrict__ krevs,
                                            int conv_blocks) {
  int kb = (int)blockIdx.x - conv_blocks;
  if (kb >= 0) {
    int u = kb * 256 + threadIdx.x;
    for (int a = 0; a < 8; ++a) {
      int t = u + a - 8;
      u16 v = 0;
      if (t >= 0 && t <= 4095) v = f2bf(kern[4095 - t]);
      krevs[a * KREV_STRIDE + u] = v;
    }
  } else {
    size_t i = ((size_t)blockIdx.x * 256 + threadIdx.x) * 8;
    const f32x4* p = (const f32x4*)(x + i);
    f32x4 v0 = p[0], v1 = p[1];
    u16x8 r;
    r[0] = f2bf(v0[0]); r[1] = f2bf(v0[1]); r[2] = f2bf(v0[2]); r[3] = f2bf(v0[3]);
    r[4] = f2bf(v1[0]); r[5] = f2bf(v1[1]); r[6] = f2bf(v1[2]); r[7] = f2bf(v1[3]);
    *(u16x8*)(xb + i) = r;
  }
}

template <bool CONV>
__global__ __launch_bounds__(512, 4) void toeplitz_gemm(const void* __restrict__ Av,
                                                        const u16* __restrict__ krevs,
                                                        float* __restrict__ out) {
  // layout: A [2 groups][128*64] = 32768 elems (65536 B is wrong -- u16: 32768 B),
  // B [2 bufs][8*520] = 8320 elems (16640 B). total 49408 B. Epilogue overlays.
  __shared__ __align__(16) char smem_raw[49408];
  u16*   A_all = (u16*)smem_raw;              // 2 x 8192 elems
  u16*   B_all = (u16*)(smem_raw + 32768);    // 2 x 4160 elems
  f32x4* ep    = (f32x4*)smem_raw;            // epilogue overlay, 9 f32x4 per slot

  const int tid  = threadIdx.x;
  const int w    = tid >> 6;        // 0..7
  const int g    = w >> 2;          // K-group 0..1
  const int wl   = w & 3;           // wave-in-group
  const int lane = tid & 63;
  const int lane16 = lane & 15;
  const int quad   = lane >> 4;
  const int wm = wl >> 1;
  const int wn = wl & 1;

  // boustrophedon: class j = b&255 gets ranks {j, 511-j} (balanced per-CU totals)
  const int b    = (int)blockIdx.x;
  const int rank = (b < 256) ? b : 511 - (b & 255);
  const int ct   = 31 - (rank >> 4);      // column tile, heavy first
  const int n0   = ct * 128;
  const int m0   = (rank & 15) * 128;
  const int W    = 3968 - n0;             // B window base for chunk 0

  // B frag: elem j = krev_logical[s0 + k], s0 = 4095-n_g+quad*8; chunk c holds
  // krev_logical[W + c*256 + u + a - 8] at copy a elem u.
  int boff[4];
  for (int fn = 0; fn < 4; ++fn) {
    int n_g = n0 + wn * 64 + fn * 16 + lane16;
    int s0  = 4095 - n_g + quad * 8;
    int a   = s0 & 7;
    boff[fn] = a * BSTRIDE + (s0 - a + 8 - W);
  }

  f32x4 acc[4][4] = {};
  const int srow8 = lane >> 3;
  const int ssrc  = ((lane & 7) ^ srow8) * 8;   // XOR source swizzle (16B chunks)

  const u16*  xb = (const u16*)Av;
  const float* xf = (const float*)Av;
  u16* A_g = A_all + g * 8192;

  auto stageA = [&](int t) {
    const int k0 = t * 128 + g * 64;
    if constexpr (CONV) {
      int j    = tid & 255;                // 256 threads per group
      int row  = j >> 1;
      int lh   = j & 1;
      for (int lc = 0; lc < 4; ++lc) {
        int l = lh * 4 + lc;
        int p = l ^ (row & 7);
        const f32x4* px = (const f32x4*)(xf + (size_t)(m0 + row) * KDIM + k0 + l * 8);
        f32x4 v0 = px[0], v1 = px[1];
        u16x8 r;
        r[0]=f2bf(v0[0]); r[1]=f2bf(v0[1]); r[2]=f2bf(v0[2]); r[3]=f2bf(v0[3]);
        r[4]=f2bf(v1[0]); r[5]=f2bf(v1[1]); r[6]=f2bf(v1[2]); r[7]=f2bf(v1[3]);
        *(u16x8*)(&A_g[row * 64 + p * 8]) = r;
      }
    } else {
      for (int c = 0; c < 4; ++c) {
        int g8  = c * 4 + wl;              // 8-row group 0..15
        int row = g8 * 8 + srow8;
        async_copy16(xb + (size_t)(m0 + row) * KDIM + k0 + ssrc,
                     &A_g[g8 * 512]);      // wave-uniform base; HW adds lane*16B
      }
    }
  };
  auto stageB = [&](int c) {               // all 8 waves, one copy each
    async_copy16(krevs + w * KREV_STRIDE + W + c * 256 + (lane << 3),
                 &B_all[(c & 1) * 4160 + w * BSTRIDE]);
  };

  // prologue
  stageB(0);
  stageA(0);

  const int cmax = ct >> 1;
  for (int t = 0; ; ++t) {
    __syncthreads();                       // stage(t) drained (vmcnt/lgkm)
    const u16* Bb  = B_all + ((t >> 1) & 1) * 4160;
    const int  ksl = (t & 1) * 128 + g * 64;
    for (int kk = 0; kk < 2; ++kk) {
      bf16x8 af[4];
      const int p = (kk * 4 + quad) ^ (lane16 & 7);
      for (int fm = 0; fm < 4; ++fm) {
        int row = wm * 64 + fm * 16 + lane16;
        af[fm] = *(const bf16x8*)(&A_g[row * 64 + p * 8]);
      }
      bf16x8 bf[4];
      for (int fn = 0; fn < 4; ++fn)
        bf[fn] = *(const bf16x8*)(&Bb[boff[fn] + ksl + kk * 32]);
      for (int fm = 0; fm < 4; ++fm)
        for (int fn = 0; fn < 4; ++fn)
          acc[fm][fn] = __builtin_amdgcn_mfma_f32_16x16x32_bf16(af[fm], bf[fn], acc[fm][fn], 0, 0, 0);
    }
    if (t == ct) break;
    __syncthreads();                       // reads of step t complete
    stageA(t + 1);
    if (!(t & 1) && ((t >> 1) + 1) <= cmax) stageB((t >> 1) + 1);
  }

  // combine: group1's partials -> group0 via LDS (2 rounds of 2 fm each)
  const int j = tid & 255;
  for (int r = 0; r < 2; ++r) {
    __syncthreads();                       // (r=0: also fences last compute reads)
    if (g == 1) {
      for (int fm2 = 0; fm2 < 2; ++fm2)
        for (int fn = 0; fn < 4; ++fn)
          ep[j * 9 + fm2 * 4 + fn] = acc[r * 2 + fm2][fn];
    }
    __syncthreads();
    if (g == 0) {
      for (int fm2 = 0; fm2 < 2; ++fm2)
        for (int fn = 0; fn < 4; ++fn)
          acc[r * 2 + fm2][fn] += ep[j * 9 + fm2 * 4 + fn];
    }
  }

  // epilogue (group 0 only): C/D layout col=lane&15, row=quad*4+r
  if (g == 0) {
    for (int fm = 0; fm < 4; ++fm) {
      int row_base = m0 + wm * 64 + fm * 16 + quad * 4;
      for (int fn = 0; fn < 4; ++fn) {
        int col = n0 + wn * 64 + fn * 16 + lane16;
        for (int r = 0; r < 4; ++r)
          out[(size_t)(row_base + r) * NDIM + col] = acc[fm][fn][r];
      }
    }
  }
}

extern "C" void kernel_launch(void* const* d_in, const int* in_sizes, int n_in,
                              void* d_out, int out_size, void* d_ws, size_t ws_size,
                              hipStream_t stream) {
  const float* x    = (const float*)d_in[0];
  const float* kern = (const float*)d_in[1];
  float* out = (float*)d_out;

  u16* krevs = (u16*)d_ws;
  u16* xb    = (u16*)((char*)d_ws + KREV_BYTES);
  const size_t need_fast = (size_t)KREV_BYTES + (size_t)MDIM * KDIM * 2;

  if (ws_size >= need_fast) {
    prep<<<4096 + 18, 256, 0, stream>>>(x, kern, xb, krevs, 4096);
    toeplitz_gemm<false><<<512, 512, 0, stream>>>(xb, krevs, out);
  } else {
    prep<<<18, 256, 0, stream>>>(x, kern, xb, krevs, 0);
    toeplitz_gemm<true><<<512, 512, 0, stream>>>(x, krevs, out);
  }
}